// Round 8
// baseline (28843.887 us; speedup 1.0000x reference)
//
#include <hip/hip_runtime.h>
#include <cmath>
#include <cstdint>

typedef unsigned long long u64;
typedef uint32_t u32;
typedef uint16_t u16;

#define NB 16
#define NT 500
#define NIN 1024
#define NN 4096
#define NWORDS 64   // NN/64
#define FWORDS 16   // NIN/64
#define NBLK 256

// Per-wave u32 offset-list regions in LDS (entries are (row<<14) byte offsets;
// 16B-aligned starts, +32 zero-pad room each):
#define E_OFF 0
#define I_OFF 3328
#define F_OFF 4224
#define L_TOT 5280   // u32 per wave -> 21120 B; x4 waves = 84480 B LDS

__global__ __launch_bounds__(256) void k_inmask(const float* __restrict__ in, u64* __restrict__ inmask){
  int idx = blockIdx.x * 256 + threadIdx.x;
  u64 bal = __ballot(in[idx] > 0.0f);
  if ((threadIdx.x & 63) == 0) inmask[idx >> 6] = bal;
}

// Zero mask triple-buffer + barrier counters; build excitatory word-mask. Grid: 16x256.
__global__ __launch_bounds__(256) void k_init(u64* __restrict__ rm, u32* __restrict__ bar,
                                              u64* __restrict__ excw, const int* __restrict__ ctype){
  int idx = blockIdx.x * 256 + threadIdx.x;   // 0..4095
  if (idx < 3 * NB * NWORDS) rm[idx] = 0ull;
  if (idx < 68 * 32) bar[idx] = 0u;           // L1[32] + L2[4] + REL[32], 128B stride
  u64 bal = __ballot(ctype[idx] == 0);
  if ((threadIdx.x & 63) == 0) excw[idx >> 6] = bal;
}

// Build ascending row-offset list ((row<<14) as u32) from a 64x64-bit mask;
// zero-pad 32 entries past the end (pads load row 0, masked to +0.0f at ACC).
__device__ __forceinline__ int build32(u64 bits, u32* __restrict__ L, int lane){
  int c = __popcll(bits), p = c;
#pragma unroll
  for (int d = 1; d < 64; d <<= 1){ int o = __shfl_up(p, d, 64); if (lane >= d) p += o; }
  int k = p - c;
  int tot = __shfl(p, 63, 64);
  u64 x = bits;
  u32 base = ((u32)lane) << 6;
  while (x){ int j = __builtin_ctzll(x); x &= x - 1; L[k++] = (base | (u32)j) << 14; }
  if (lane < 32) L[tot + lane] = 0u;
  return tot;
}

// Issue 32 scheduler-proof loads for group g into buf (volatile asm: issue
// order is program order; result regs stay live until consumed).
#define G_LOAD(buf, g) { \
    const uint4* q4_ = (const uint4*)(Lp + ((g) << 5)); \
    _Pragma("unroll") \
    for (int q = 0; q < 8; ++q){ \
      uint4 pk = q4_[q]; \
      u32 o0 = pk.x + m4, o1 = pk.y + m4, o2 = pk.z + m4, o3 = pk.w + m4; \
      asm volatile("global_load_dword %0, %1, %2" : "=v"(buf[q*4+0]) : "v"(o0), "s"(Wb)); \
      asm volatile("global_load_dword %0, %1, %2" : "=v"(buf[q*4+1]) : "v"(o1), "s"(Wb)); \
      asm volatile("global_load_dword %0, %1, %2" : "=v"(buf[q*4+2]) : "v"(o2), "s"(Wb)); \
      asm volatile("global_load_dword %0, %1, %2" : "=v"(buf[q*4+3]) : "v"(o3), "s"(Wb)); \
    } }

// Counted wait + sched_barrier(0) (rule #18: stop reg-only fadds hoisting above).
#define WAIT_VM(N) { asm volatile("s_waitcnt vmcnt(" #N ")"); __builtin_amdgcn_sched_barrier(0); }

// Strict ascending-order add of group g (tail pads -> +0.0f, bitwise identity).
#define ACCR(buf, g) { \
    if ((g) == ngrp - 1 && rem){ \
      _Pragma("unroll") \
      for (int j = 0; j < 32; ++j){ float pv_ = (j < rem) ? buf[j] : 0.0f; acc = __fadd_rn(acc, pv_); } \
    } else { \
      _Pragma("unroll") \
      for (int j = 0; j < 32; ++j) acc = __fadd_rn(acc, buf[j]); \
    } }

// Sequential ascending-n fp32 add chain; hand-built 2x32 load pipeline
// (~64 outstanding wave-loads, HW cap 63). Bitwise identical to a plain
// ascending loop: only load issue is reordered; adds stay in order.
__device__ __forceinline__ float chain_asm(u64 Wb, const u32* __restrict__ Lp,
                                           int cnt, u32 m4)
{
  float acc = 0.0f;
  const int ngrp = (cnt + 31) >> 5;
  if (ngrp <= 0) return acc;
  const int rem = cnt & 31;
  float A[32], B[32];

  G_LOAD(A, 0)
  if (ngrp > 1) G_LOAD(B, 1)
  int g = 0;
  for (;;){
    if (g + 1 < ngrp) { WAIT_VM(32) } else { WAIT_VM(0) }
    ACCR(A, g)
    if (++g == ngrp) break;
    if (g + 1 < ngrp) G_LOAD(A, g + 1)
    if (g + 1 < ngrp) { WAIT_VM(32) } else { WAIT_VM(0) }
    ACCR(B, g)
    if (++g == ngrp) break;
    if (g + 1 < ngrp) G_LOAD(B, g + 1)
  }
  return acc;
}

// All 500 steps in one kernel. 256 blocks x 256 threads, all co-resident.
// waves_per_eu(1,1): full VGPR budget (no spill of the 64-float pipeline).
// Blocks bk>>6 form 4 independent batch-groups; two-level barrier per group.
__global__ __attribute__((amdgpu_flat_work_group_size(256, 256), amdgpu_waves_per_eu(1, 1)))
void k_fused(
    const float* __restrict__ W, const float* __restrict__ Wff,
    const u64* __restrict__ excw, const u64* __restrict__ inmask,
    u64* __restrict__ rm, u32* __restrict__ bar,
    float* __restrict__ out,
    float a0, float a1, float aff, float beta, float omb)
{
  const int lane = threadIdx.x & 63;
  const int wv   = threadIdx.x >> 6;                 // local batch 0..3
  const int bk   = blockIdx.x;
  // XCD-aware: xcd = bk&7 -> XCD x owns columns [x*512, x*512+512) for all batches
  const int xcd   = bk & 7;
  const int chunk = xcd * 8 + ((bk >> 3) & 7);       // 0..63
  const int grp   = bk >> 6;                         // batch-group 0..3
  const int b     = grp * 4 + wv;                    // 0..15
  const int m     = chunk * 64 + lane;               // 0..4095
  const u32 m4    = (u32)(m << 2);
  const bool lead = ((bk >> 3) & 7) == 0;            // one leader per (grp,xcd)

  __shared__ __align__(16) u32 lst[4][L_TOT];
  u32* Lb = lst[wv];

  const u64 Wb  = (u64)(uintptr_t)W;
  const u64 Wfb = (u64)(uintptr_t)Wff;
  const u64 ew = excw[lane];
  u32* l1  = bar + (size_t)(grp * 8 + xcd) * 32;        // 8 blocks, same XCD
  u32* l2  = bar + (size_t)(32 + grp) * 32;             // 8 leaders, cross XCD
  u32* rel = bar + (size_t)(36 + grp * 8 + xcd) * 32;   // release word, same XCD

  float vv = 0.0f, xi0 = 0.0f, xi1 = 0.0f, xff = 0.0f, rv = 0.0f;

  for (int t = 0; t < NT; ++t){
    u64* rcur = rm + (size_t)(t % 3)       * (NB * NWORDS);
    u64* rnxt = rm + (size_t)((t + 1) % 3) * (NB * NWORDS);

    u64 bits = __hip_atomic_load(&rcur[b * NWORDS + lane],
                                 __ATOMIC_RELAXED, __HIP_MEMORY_SCOPE_AGENT);
    u64 be = bits & ew;
    u64 bi = bits & ~ew;
    u64 bf = (lane < FWORDS) ? inmask[((size_t)b * NT + t) * FWORDS + lane] : 0ull;

    int tot_e = build32(be, Lb + E_OFF, lane);
    int tot_i = build32(bi, Lb + I_OFF, lane);
    int tot_f = build32(bf, Lb + F_OFF, lane);

    float de = chain_asm(Wb,  Lb + E_OFF, tot_e, m4);
    float di = chain_asm(Wb,  Lb + I_OFF, tot_i, m4);
    float df = chain_asm(Wfb, Lb + F_OFF, tot_f, m4);

    // I = alpha*I + drive  (separate mul/add roundings; -(sum of +W) == sum of -W bitwise)
    xi0 = __fadd_rn(__fmul_rn(a0,  xi0), de);
    xi1 = __fadd_rn(__fmul_rn(a1,  xi1), -di);
    xff = __fadd_rn(__fmul_rn(aff, xff), df);
    float itot = __fadd_rn(__fadd_rn(xi0, xi1), xff);
    float vn = (rv <= 0.0f) ? __fadd_rn(__fmul_rn(beta, vv), __fmul_rn(omb, itot)) : 0.0f;
    bool s = vn > 1.0f;                 // == (v_new - 1 > 0) exactly
    rv = s ? 2.0f : fmaxf(rv - 1.0f, 0.0f);
    vv = s ? 0.0f : vn;
    out[(size_t)b * NT * NN + (size_t)t * NN + m] = s ? 1.0f : 0.0f;

    u64 bal = __ballot(s);              // wave covers word 'chunk' of batch b
    if (lane == 0)
      __hip_atomic_store(&rnxt[b * NWORDS + chunk], bal,
                         __ATOMIC_RELAXED, __HIP_MEMORY_SCOPE_AGENT);

    // ---- two-level per-group barrier (8 local + 8 cross-XCD + local release) ----
    __syncthreads();
    if (threadIdx.x == 0){
      const u32 tgt = (u32)(t + 1) * 8;
      __hip_atomic_fetch_add(l1, 1u, __ATOMIC_ACQ_REL, __HIP_MEMORY_SCOPE_AGENT);
      if (lead){
        while (__hip_atomic_load(l1, __ATOMIC_ACQUIRE, __HIP_MEMORY_SCOPE_AGENT) < tgt)
          __builtin_amdgcn_s_sleep(1);
        __hip_atomic_fetch_add(l2, 1u, __ATOMIC_ACQ_REL, __HIP_MEMORY_SCOPE_AGENT);
        while (__hip_atomic_load(l2, __ATOMIC_ACQUIRE, __HIP_MEMORY_SCOPE_AGENT) < tgt)
          __builtin_amdgcn_s_sleep(1);
        __hip_atomic_store(rel, (u32)(t + 1), __ATOMIC_RELEASE, __HIP_MEMORY_SCOPE_AGENT);
      } else {
        while (__hip_atomic_load(rel, __ATOMIC_ACQUIRE, __HIP_MEMORY_SCOPE_AGENT) < (u32)(t + 1))
          __builtin_amdgcn_s_sleep(1);
      }
    }
    __syncthreads();
  }
}

extern "C" void kernel_launch(void* const* d_in, const int* in_sizes, int n_in,
                              void* d_out, int out_size, void* d_ws, size_t ws_size,
                              hipStream_t stream)
{
  const float* in_sp = (const float*)d_in[0];   // [16,500,1024]
  const float* W     = (const float*)d_in[1];   // [4096,4096]
  const float* Wff   = (const float*)d_in[2];   // [1024,4096]
  const int*   ctype = (const int*)d_in[3];     // [4096]
  float* out = (float*)d_out;

  char* ws = (char*)d_ws;
  u64* rm     = (u64*)ws;                                   // [3][NB][NWORDS]
  size_t off  = (size_t)3 * NB * NWORDS * 8;
  u64* excw   = (u64*)(ws + off); off += (size_t)NWORDS * 8;
  u64* inmask = (u64*)(ws + off); off += (size_t)NB * NT * FWORDS * 8;
  u32* bar    = (u32*)(ws + off); off += 68 * 32 * sizeof(u32);

  // Constants matching numpy semantics (validated bit-exact rounds 1-4):
  float af  = -1.0f / 5.0f;
  float bf  = -1.0f / 10.0f;
  float a0  = (float)std::exp((double)af);
  float a1  = (float)std::exp((double)bf);
  float aff = (float)std::exp(-1.0 / 5.0);
  float beta = (float)std::exp(-1.0 / 20.0);
  float omb  = 1.0f - beta;   // exact (Sterbenz)

  k_inmask<<<(NB * NT * NIN) / 256, 256, 0, stream>>>(in_sp, inmask);
  k_init<<<16, 256, 0, stream>>>(rm, bar, excw, ctype);
  k_fused<<<NBLK, 256, 0, stream>>>(W, Wff, excw, inmask, rm, bar, out,
                                    a0, a1, aff, beta, omb);
}